// Round 5
// baseline (204.749 us; speedup 1.0000x reference)
//
#include <hip/hip_runtime.h>
#include <math.h>

#define N_NODES 100000
#define N_EDGES 3200000
#define IN_DIM 128
#define HG 64

#define E0CAP 2048      // capacity for edges into node 0 (expected ~32)
#define MCAP  65536     // capacity for edges into S1 nodes (expected ~1100)
#define NBMW  3125      // bitmap words: ceil(100000/32)
#define SCAN_BLOCKS 1024
#define BLK_E0 16       // per-block capacity for dst==0 hits (expected 0.03)
#define CF_BLOCKS 384   // contrib blocks: 384*4 = 1536 wave-workers

// workspace layout; [0, WS_ZERO_BYTES) zeroed by k_scan0 grid-stride
#define OFF_DEG       0u          // int[N_NODES]            400000
#define OFF_SLOTMAP   400000u     // int[N_NODES]            400000
#define OFF_CNT       800000u     // int[8]: n0,ns,m,fin     32
#define OFF_ACC       800032u     // float[E0CAP*HG]         524288
#define OFF_BMS1      1324320u    // uint[NBMW] pad          12544
#define OFF_BMNEED    1336864u    // uint[NBMW] pad          12544
#define WS_ZERO_BYTES 1349408u
#define OFF_BCNT      1349408u    // int[SCAN_BLOCKS]        4096
#define OFF_BLIST     1353504u    // int[SCAN_BLOCKS*BLK_E0] 65536
#define OFF_EDGES0    1419040u    // int[E0CAP]              8192
#define OFF_SLOTNODE  1427232u    // int[E0CAP]              8192
#define OFF_MLIST     1435424u    // int[MCAP]               262144

__device__ __forceinline__ float dinv_of(int degv) {
    // reference: deg = indeg + 1 (self loop), dinv = 1/sqrt(deg), always >= 1
    return 1.0f / sqrtf((float)(degv + 1));
}

// Pass 1: zero ws counters/acc (replaces hipMemsetAsync) and scan dst for
// edges into node 0, compacting per-block (no global counter).
__global__ void k_scan0(const int* __restrict__ src, const int* __restrict__ dst,
                        int4* __restrict__ zbase, int* __restrict__ bcnt,
                        int* __restrict__ blist) {
    __shared__ int lcnt;
    __shared__ int lsrc[BLK_E0];
    if (threadIdx.x == 0) lcnt = 0;
    __syncthreads();
    int tid = blockIdx.x * blockDim.x + threadIdx.x;
    int nth = gridDim.x * blockDim.x;
    const int nz = WS_ZERO_BYTES / 16;
    int4 z; z.x = 0; z.y = 0; z.z = 0; z.w = 0;
    for (int i = tid; i < nz; i += nth) zbase[i] = z;
    const int4* dst4 = (const int4*)dst;
    const int n4 = N_EDGES / 4;
    for (int i = tid; i < n4; i += nth) {
        int4 dv = dst4[i];
        int ds[4] = {dv.x, dv.y, dv.z, dv.w};
#pragma unroll
        for (int k = 0; k < 4; k++) {
            if (ds[k] == 0) {
                int p = atomicAdd(&lcnt, 1);
                if (p < BLK_E0) lsrc[p] = src[4 * i + k];
            }
        }
    }
    __syncthreads();
    int c = lcnt; if (c > BLK_E0) c = BLK_E0;
    if (threadIdx.x == 0) bcnt[blockIdx.x] = c;
    for (int i = threadIdx.x; i < c; i += blockDim.x)
        blist[blockIdx.x * BLK_E0 + i] = lsrc[i];
}

// Pass 2 (1 block): gather per-block lists -> dense edges0, dedupe -> slots,
// build S1 bitmap.
__global__ void k_build_slots(const int* __restrict__ bcnt, const int* __restrict__ blist,
                              int* __restrict__ edges0, int* __restrict__ slotnodes,
                              int* __restrict__ slotmap, int* __restrict__ cnt,
                              unsigned* __restrict__ bmS1) {
    const int t = threadIdx.x;
    for (int b = t; b < SCAN_BLOCKS; b += blockDim.x) {
        int c = bcnt[b];
        if (c > 0) {
            int p = atomicAdd(&cnt[0], c);
            for (int j = 0; j < c && p + j < E0CAP; j++)
                edges0[p + j] = blist[b * BLK_E0 + j];
        }
    }
    __syncthreads();
    int n0 = atomicAdd(&cnt[0], 0); if (n0 > E0CAP) n0 = E0CAP;
    for (int i = t; i < n0 + 1; i += blockDim.x) {
        int s = (i == n0) ? 0 : edges0[i];
        if (atomicCAS(&slotmap[s], 0, 1) == 0) {
            int p = atomicAdd(&cnt[1], 1);
            if (p < E0CAP) slotnodes[p] = s;
        }
    }
    __syncthreads();
    int ns = atomicAdd(&cnt[1], 0); if (ns > E0CAP) ns = E0CAP;
    for (int i = t; i < ns; i += blockDim.x) {
        int s = slotnodes[i];
        slotmap[s] = i + 1;
        atomicOr(&bmS1[s >> 5], 1u << (s & 31));
    }
}

// Pass 3: LDS-bitmap probe for dst in S1 -> mlist; mark srcs in bmNeed.
__global__ void k_match(const int* __restrict__ src, const int* __restrict__ dst,
                        const unsigned* __restrict__ bmS1, unsigned* __restrict__ bmNeed,
                        int* __restrict__ cnt, int* __restrict__ mlist) {
    __shared__ unsigned sbm[NBMW];
    for (int i = threadIdx.x; i < NBMW; i += blockDim.x) sbm[i] = bmS1[i];
    __syncthreads();
    int tid = blockIdx.x * blockDim.x + threadIdx.x;
    int nth = gridDim.x * blockDim.x;
    const int4* dst4 = (const int4*)dst;
    const int n4 = N_EDGES / 4;
    for (int i = tid; i < n4; i += nth) {
        int4 dv = dst4[i];
        unsigned ds[4] = {(unsigned)dv.x, (unsigned)dv.y, (unsigned)dv.z, (unsigned)dv.w};
#pragma unroll
        for (int k = 0; k < 4; k++) {
            unsigned d = ds[k];
            if ((sbm[d >> 5] >> (d & 31)) & 1u) {
                int e = 4 * i + k;
                int p = atomicAdd(&cnt[2], 1);
                if (p < MCAP) mlist[p] = e;
                int s = src[e];
                atomicOr(&bmNeed[s >> 5], 1u << (s & 31));
            }
        }
    }
}

// Pass 4: filtered in-degree via LDS bitmap (S1 | need).
__global__ void k_deg_need(const int* __restrict__ dst, const unsigned* __restrict__ bmS1,
                           const unsigned* __restrict__ bmNeed, int* __restrict__ deg) {
    __shared__ unsigned sbm[NBMW];
    for (int i = threadIdx.x; i < NBMW; i += blockDim.x) sbm[i] = bmS1[i] | bmNeed[i];
    __syncthreads();
    int tid = blockIdx.x * blockDim.x + threadIdx.x;
    int nth = gridDim.x * blockDim.x;
    const int4* dst4 = (const int4*)dst;
    const int n4 = N_EDGES / 4;
    for (int i = tid; i < n4; i += nth) {
        int4 dv = dst4[i];
        unsigned ds[4] = {(unsigned)dv.x, (unsigned)dv.y, (unsigned)dv.z, (unsigned)dv.w};
#pragma unroll
        for (int k = 0; k < 4; k++) {
            unsigned d = ds[k];
            if ((sbm[d >> 5] >> (d & 31)) & 1u) atomicAdd(&deg[d], 1);
        }
    }
}

// Pass 5 (fused): edge contributions with parallel-line x gather via LDS,
// then last block runs the epilogue.
#define CHUNK 256
__global__ void __launch_bounds__(256, 1)
k_contrib_final(const int* __restrict__ src, const int* __restrict__ dst,
                const int* __restrict__ deg, const int* __restrict__ slotmap,
                int* __restrict__ cnt, const int* __restrict__ mlist,
                const int* __restrict__ slotnodes, const int* __restrict__ edges0,
                const float* __restrict__ x, const float* __restrict__ W1,
                const float* __restrict__ b1, const float* __restrict__ W2,
                const float* __restrict__ b2, const float* __restrict__ w_ih,
                const float* __restrict__ b_ih, const float* __restrict__ b_hh,
                const float* __restrict__ fc_w, const float* __restrict__ fc_b,
                float* __restrict__ acc, float* __restrict__ out) {
    __shared__ float w1s[IN_DIM * HG];      // 32 KB, block-shared copy of W1
    __shared__ float xbuf[4][IN_DIM];       // per-wave x-column staging
    const int t = threadIdx.x;
    const int j = t & 63;        // channel / lane
    const int wv = t >> 6;       // wave in block

    // stage W1 -> LDS (coalesced float4)
    {
        const float4* w4 = (const float4*)W1;
        float4* s4 = (float4*)w1s;
        for (int i = t; i < IN_DIM * HG / 4; i += 256) s4[i] = w4[i];
    }
    __syncthreads();

    int m = cnt[2]; if (m > MCAP) m = MCAP;
    int ns = cnt[1]; if (ns > E0CAP) ns = E0CAP;
    const int total = m + ns;
    const int wk = (blockIdx.x << 2) | wv;
    const int nwk = gridDim.x << 2;
    for (int ii = wk; ii < total; ii += nwk) {
        int s, sl;
        float w;
        if (ii < m) {
            int e = mlist[ii];
            s = src[e];
            int d = dst[e];
            sl = slotmap[d] - 1;
            w = dinv_of(deg[s]) * dinv_of(deg[d]);
        } else {
            sl = ii - m;
            s = slotnodes[sl];
            float dv = dinv_of(deg[s]);
            w = dv * dv;
        }
        // parallel gather: lane j fetches rows j and j+64 of column s
        float xa = x[(size_t)j * N_NODES + s];
        float xb = x[(size_t)(j + 64) * N_NODES + s];
        xbuf[wv][j] = xa;
        xbuf[wv][j + 64] = xb;
        // wave-private LDS; compiler inserts lgkmcnt waits (no barrier needed)
        const float4* xb4 = (const float4*)xbuf[wv];
        float g = 0.f;
#pragma unroll 4
        for (int k4 = 0; k4 < IN_DIM / 4; k4++) {
            float4 xv = xb4[k4];
            g = fmaf(xv.x, w1s[(4 * k4 + 0) * HG + j], g);
            g = fmaf(xv.y, w1s[(4 * k4 + 1) * HG + j], g);
            g = fmaf(xv.z, w1s[(4 * k4 + 2) * HG + j], g);
            g = fmaf(xv.w, w1s[(4 * k4 + 3) * HG + j], g);
        }
        atomicAdd(&acc[sl * HG + j], g * w);
    }

    // last-block handoff
    __syncthreads();
    __threadfence();
    __shared__ int amLast;
    if (t == 0) amLast = (atomicAdd(&cnt[3], 1) == (int)gridDim.x - 1);
    __syncthreads();
    if (!amLast) return;

    // ---- epilogue (single block, 256 threads) ----
    __shared__ int   sh_sl[CHUNK];
    __shared__ float sh_w[CHUNK];
    __shared__ float partial[4][HG];
    __shared__ float agg[HG];
    __shared__ float zv[HG];
    __shared__ float gates[4 * HG];
    __shared__ float hw[HG];
    const int ch = j;
    const int grp = wv;
    int n0 = cnt[0]; if (n0 > E0CAP) n0 = E0CAP;

    const float dinv0 = dinv_of(deg[0]);
    const float bch = b1[ch];

    float a = 0.f;
    for (int base = 0; base < n0; base += CHUNK) {
        int cn = n0 - base; if (cn > CHUNK) cn = CHUNK;
        __syncthreads();
        if (t < cn) {
            int s = edges0[base + t];
            sh_sl[t] = slotmap[s] - 1;
            sh_w[t] = dinv_of(deg[s]) * dinv0;
        }
        __syncthreads();
        for (int i = grp; i < cn; i += 4) {
            float h = atomicAdd(&acc[sh_sl[i] * HG + ch], 0.f) + bch;
            a = fmaf(sh_w[i], (h > 0.f ? h : 0.f), a);
        }
    }
    partial[grp][ch] = a;
    __syncthreads();
    if (t < HG) {
        int sl0 = slotmap[0] - 1;
        float h0 = atomicAdd(&acc[sl0 * HG + t], 0.f) + b1[t];
        float s = dinv0 * dinv0 * (h0 > 0.f ? h0 : 0.f);
        s += partial[0][t] + partial[1][t] + partial[2][t] + partial[3][t];
        agg[t] = s;
    }
    __syncthreads();

    if (t < HG) {
        float zz = b2[t];
#pragma unroll 8
        for (int k = 0; k < HG; k++) zz = fmaf(agg[k], W2[k * HG + t], zz);
        zv[t] = zz;
    }
    __syncthreads();

    {
        float gt = b_ih[t] + b_hh[t];
#pragma unroll 8
        for (int jj = 0; jj < HG; jj++) gt = fmaf(zv[jj], w_ih[t * HG + jj], gt);
        gates[t] = gt;
    }
    __syncthreads();

    if (t < HG) {
        float ig = 1.f / (1.f + expf(-gates[t]));
        float gg = tanhf(gates[2 * HG + t]);
        float og = 1.f / (1.f + expf(-gates[3 * HG + t]));
        float c = ig * gg;
        float hy = og * tanhf(c);
        hw[t] = hy * fc_w[t];
    }
    __syncthreads();
    if (t == 0) {
        float y = fc_b[0];
        for (int jj = 0; jj < HG; jj++) y += hw[jj];
        out[0] = y;
    }
}

extern "C" void kernel_launch(void* const* d_in, const int* in_sizes, int n_in,
                              void* d_out, int out_size, void* d_ws, size_t ws_size,
                              hipStream_t stream) {
    const float* x    = (const float*)d_in[0];
    const int*   ei   = (const int*)d_in[1];
    const float* W1   = (const float*)d_in[2];
    const float* b1   = (const float*)d_in[3];
    const float* W2   = (const float*)d_in[4];
    const float* b2   = (const float*)d_in[5];
    const float* w_ih = (const float*)d_in[6];
    // d_in[7] = w_hh, unused (h0 = 0)
    const float* b_ih = (const float*)d_in[8];
    const float* b_hh = (const float*)d_in[9];
    const float* fc_w = (const float*)d_in[10];
    const float* fc_b = (const float*)d_in[11];
    float* out = (float*)d_out;

    const int* src = ei;
    const int* dst = ei + N_EDGES;

    char* ws = (char*)d_ws;
    int*      deg       = (int*)(ws + OFF_DEG);
    int*      slotmap   = (int*)(ws + OFF_SLOTMAP);
    int*      cnt       = (int*)(ws + OFF_CNT);
    float*    acc       = (float*)(ws + OFF_ACC);
    unsigned* bmS1      = (unsigned*)(ws + OFF_BMS1);
    unsigned* bmNeed    = (unsigned*)(ws + OFF_BMNEED);
    int*      bcnt      = (int*)(ws + OFF_BCNT);
    int*      blist     = (int*)(ws + OFF_BLIST);
    int*      edges0    = (int*)(ws + OFF_EDGES0);
    int*      slotnodes = (int*)(ws + OFF_SLOTNODE);
    int*      mlist     = (int*)(ws + OFF_MLIST);

    k_scan0<<<SCAN_BLOCKS, 256, 0, stream>>>(src, dst, (int4*)ws, bcnt, blist);
    k_build_slots<<<1, 256, 0, stream>>>(bcnt, blist, edges0, slotnodes, slotmap, cnt, bmS1);
    k_match<<<SCAN_BLOCKS, 256, 0, stream>>>(src, dst, bmS1, bmNeed, cnt, mlist);
    k_deg_need<<<SCAN_BLOCKS, 256, 0, stream>>>(dst, bmS1, bmNeed, deg);
    k_contrib_final<<<CF_BLOCKS, 256, 0, stream>>>(src, dst, deg, slotmap, cnt, mlist,
                                                   slotnodes, edges0, x, W1, b1, W2, b2,
                                                   w_ih, b_ih, b_hh, fc_w, fc_b, acc, out);
}

// Round 6
// 168.442 us; speedup vs baseline: 1.2155x; 1.2155x over previous
//
#include <hip/hip_runtime.h>
#include <math.h>

#define N_NODES 100000
#define N_EDGES 3200000
#define IN_DIM 128
#define HG 64

#define E0CAP 2048      // capacity for edges into node 0 (expected ~32)
#define MCAP  65536     // capacity for edges into S1 nodes (expected ~1100)
#define NBMW  3125      // bitmap words: ceil(100000/32)
#define SCAN_BLOCKS 1024
#define BLK_E0 16       // per-block capacity for dst==0 hits (expected 0.03)

// workspace layout; [0, WS_ZERO_BYTES) zeroed by k_scan0 grid-stride
#define OFF_DEG       0u          // int[N_NODES]            400000
#define OFF_SLOTMAP   400000u     // int[N_NODES]            400000
#define OFF_CNT       800000u     // int[8]: n0,ns,m         32
#define OFF_ACC       800032u     // float[E0CAP*HG]         524288
#define OFF_BMS1      1324320u    // uint[NBMW] pad          12544
#define OFF_BMNEED    1336864u    // uint[NBMW] pad          12544
#define WS_ZERO_BYTES 1349408u
#define OFF_BCNT      1349408u    // int[SCAN_BLOCKS]        4096
#define OFF_BLIST     1353504u    // int[SCAN_BLOCKS*BLK_E0] 65536
#define OFF_EDGES0    1419040u    // int[E0CAP]              8192
#define OFF_SLOTNODE  1427232u    // int[E0CAP]              8192
#define OFF_MLISTS    1435424u    // int[MCAP]  s | slot<<17 262144
#define OFF_MLISTD    1697568u    // int[MCAP]  d            262144

__device__ __forceinline__ float dinv_of(int degv) {
    // reference: deg = indeg + 1 (self loop), dinv = 1/sqrt(deg), always >= 1
    return 1.0f / sqrtf((float)(degv + 1));
}

// Pass 1: zero ws counters/acc/bitmaps (replaces hipMemsetAsync) and scan dst
// for edges into node 0, compacting per-block (no global counter).
__global__ void k_scan0(const int* __restrict__ src, const int* __restrict__ dst,
                        int4* __restrict__ zbase, int* __restrict__ bcnt,
                        int* __restrict__ blist) {
    __shared__ int lcnt;
    __shared__ int lsrc[BLK_E0];
    if (threadIdx.x == 0) lcnt = 0;
    __syncthreads();
    int tid = blockIdx.x * blockDim.x + threadIdx.x;
    int nth = gridDim.x * blockDim.x;
    const int nz = WS_ZERO_BYTES / 16;
    int4 z; z.x = 0; z.y = 0; z.z = 0; z.w = 0;
    for (int i = tid; i < nz; i += nth) zbase[i] = z;
    const int4* dst4 = (const int4*)dst;
    const int n4 = N_EDGES / 4;
    for (int i = tid; i < n4; i += nth) {
        int4 dv = dst4[i];
        int ds[4] = {dv.x, dv.y, dv.z, dv.w};
#pragma unroll
        for (int k = 0; k < 4; k++) {
            if (ds[k] == 0) {
                int p = atomicAdd(&lcnt, 1);
                if (p < BLK_E0) lsrc[p] = src[4 * i + k];
            }
        }
    }
    __syncthreads();
    int c = lcnt; if (c > BLK_E0) c = BLK_E0;
    if (threadIdx.x == 0) bcnt[blockIdx.x] = c;
    for (int i = threadIdx.x; i < c; i += blockDim.x)
        blist[blockIdx.x * BLK_E0 + i] = lsrc[i];
}

// Pass 2 (1 block): gather per-block lists -> dense edges0, dedupe -> slots,
// build S1 bitmap.
__global__ void k_build_slots(const int* __restrict__ bcnt, const int* __restrict__ blist,
                              int* __restrict__ edges0, int* __restrict__ slotnodes,
                              int* __restrict__ slotmap, int* __restrict__ cnt,
                              unsigned* __restrict__ bmS1) {
    const int t = threadIdx.x;
    for (int b = t; b < SCAN_BLOCKS; b += blockDim.x) {
        int c = bcnt[b];
        if (c > 0) {
            int p = atomicAdd(&cnt[0], c);
            for (int j = 0; j < c && p + j < E0CAP; j++)
                edges0[p + j] = blist[b * BLK_E0 + j];
        }
    }
    __syncthreads();
    int n0 = atomicAdd(&cnt[0], 0); if (n0 > E0CAP) n0 = E0CAP;
    for (int i = t; i < n0 + 1; i += blockDim.x) {
        int s = (i == n0) ? 0 : edges0[i];
        if (atomicCAS(&slotmap[s], 0, 1) == 0) {
            int p = atomicAdd(&cnt[1], 1);
            if (p < E0CAP) slotnodes[p] = s;
        }
    }
    __syncthreads();
    int ns = atomicAdd(&cnt[1], 0); if (ns > E0CAP) ns = E0CAP;
    for (int i = t; i < ns; i += blockDim.x) {
        int s = slotnodes[i];
        slotmap[s] = i + 1;
        atomicOr(&bmS1[s >> 5], 1u << (s & 31));
    }
}

// Pass 3: LDS-bitmap probe for dst in S1 -> packed task records; mark srcs
// in bmNeed. Record: mlistS = s | slot<<17, mlistD = d.
__global__ void k_match(const int* __restrict__ src, const int* __restrict__ dst,
                        const int* __restrict__ slotmap,
                        const unsigned* __restrict__ bmS1, unsigned* __restrict__ bmNeed,
                        int* __restrict__ cnt, int* __restrict__ mlistS,
                        int* __restrict__ mlistD) {
    __shared__ unsigned sbm[NBMW];
    for (int i = threadIdx.x; i < NBMW; i += blockDim.x) sbm[i] = bmS1[i];
    __syncthreads();
    int tid = blockIdx.x * blockDim.x + threadIdx.x;
    int nth = gridDim.x * blockDim.x;
    const int4* dst4 = (const int4*)dst;
    const int n4 = N_EDGES / 4;
    for (int i = tid; i < n4; i += nth) {
        int4 dv = dst4[i];
        unsigned ds[4] = {(unsigned)dv.x, (unsigned)dv.y, (unsigned)dv.z, (unsigned)dv.w};
#pragma unroll
        for (int k = 0; k < 4; k++) {
            unsigned d = ds[k];
            if ((sbm[d >> 5] >> (d & 31)) & 1u) {
                int e = 4 * i + k;
                int s = src[e];
                int sl = slotmap[d] - 1;
                int p = atomicAdd(&cnt[2], 1);
                if (p < MCAP) {
                    mlistS[p] = s | (sl << 17);
                    mlistD[p] = (int)d;
                }
                atomicOr(&bmNeed[s >> 5], 1u << (s & 31));
            }
        }
    }
}

// Pass 4: filtered in-degree via LDS bitmap (S1 | need).
__global__ void k_deg_need(const int* __restrict__ dst, const unsigned* __restrict__ bmS1,
                           const unsigned* __restrict__ bmNeed, int* __restrict__ deg) {
    __shared__ unsigned sbm[NBMW];
    for (int i = threadIdx.x; i < NBMW; i += blockDim.x) sbm[i] = bmS1[i] | bmNeed[i];
    __syncthreads();
    int tid = blockIdx.x * blockDim.x + threadIdx.x;
    int nth = gridDim.x * blockDim.x;
    const int4* dst4 = (const int4*)dst;
    const int n4 = N_EDGES / 4;
    for (int i = tid; i < n4; i += nth) {
        int4 dv = dst4[i];
        unsigned ds[4] = {(unsigned)dv.x, (unsigned)dv.y, (unsigned)dv.z, (unsigned)dv.w};
#pragma unroll
        for (int k = 0; k < 4; k++) {
            unsigned d = ds[k];
            if ((sbm[d >> 5] >> (d & 31)) & 1u) atomicAdd(&deg[d], 1);
        }
    }
}

// Pass 5: edge contributions. One 64-thread block per virtual task
// (task = edge or self-loop, split into two K-halves of 64 rows each).
// Broadcast x loads, fully unrolled so ~64 independent lines are in flight.
__global__ void k_contrib(const int* __restrict__ deg, const int* __restrict__ cnt,
                          const int* __restrict__ mlistS, const int* __restrict__ mlistD,
                          const int* __restrict__ slotnodes,
                          const float* __restrict__ x, const float* __restrict__ W1,
                          float* __restrict__ acc) {
    int m = cnt[2]; if (m > MCAP) m = MCAP;
    int ns = cnt[1]; if (ns > E0CAP) ns = E0CAP;
    const int vtotal = 2 * (m + ns);
    const int j = threadIdx.x;  // 0..63 output channel
    for (int v = blockIdx.x; v < vtotal; v += gridDim.x) {
        const int ii = v >> 1;
        const int kbase = (v & 1) << 6;  // 0 or 64
        int s, sl;
        float w;
        if (ii < m) {
            int sw = mlistS[ii];
            int d = mlistD[ii];
            s = sw & 0x1FFFF;
            sl = sw >> 17;
            w = dinv_of(deg[s]) * dinv_of(deg[d]);
        } else {
            sl = ii - m;
            s = slotnodes[sl];
            float dv = dinv_of(deg[s]);
            w = dv * dv;
        }
        const float* xp = x + (size_t)kbase * N_NODES + s;
        const float* wp = W1 + kbase * HG + j;
        float g = 0.f;
#pragma unroll
        for (int k = 0; k < 64; k++) {
            g = fmaf(xp[(size_t)k * N_NODES], wp[k * HG], g);
        }
        atomicAdd(&acc[sl * HG + j], g * w);
    }
}

// Pass 6: layer-2 agg at node 0 (relu+bias inline), W2 matvec, LSTM, FC.
#define CHUNK 256
__global__ void k_final(const float* __restrict__ b1, const float* __restrict__ W2,
                        const float* __restrict__ b2, const float* __restrict__ w_ih,
                        const float* __restrict__ b_ih, const float* __restrict__ b_hh,
                        const float* __restrict__ fc_w, const float* __restrict__ fc_b,
                        const int* __restrict__ deg, const int* __restrict__ slotmap,
                        const int* __restrict__ cnt, const int* __restrict__ edges0,
                        const float* __restrict__ acc, float* __restrict__ out) {
    __shared__ int   sh_sl[CHUNK];
    __shared__ float sh_w[CHUNK];
    __shared__ float partial[4][HG];
    __shared__ float agg[HG];
    __shared__ float zv[HG];
    __shared__ float gates[4 * HG];
    __shared__ float hw[HG];
    const int t = threadIdx.x;
    const int ch = t & (HG - 1);
    const int grp = t >> 6;
    int n0 = cnt[0]; if (n0 > E0CAP) n0 = E0CAP;

    const float dinv0 = dinv_of(deg[0]);
    const float bch = b1[ch];

    float a = 0.f;
    for (int base = 0; base < n0; base += CHUNK) {
        int cn = n0 - base; if (cn > CHUNK) cn = CHUNK;
        __syncthreads();
        if (t < cn) {
            int s = edges0[base + t];
            sh_sl[t] = slotmap[s] - 1;
            sh_w[t] = dinv_of(deg[s]) * dinv0;
        }
        __syncthreads();
        for (int i = grp; i < cn; i += 4) {
            float h = acc[sh_sl[i] * HG + ch] + bch;
            a = fmaf(sh_w[i], (h > 0.f ? h : 0.f), a);
        }
    }
    partial[grp][ch] = a;
    __syncthreads();
    if (t < HG) {
        int sl0 = slotmap[0] - 1;
        float h0 = acc[sl0 * HG + t] + b1[t];
        float s = dinv0 * dinv0 * (h0 > 0.f ? h0 : 0.f);
        s += partial[0][t] + partial[1][t] + partial[2][t] + partial[3][t];
        agg[t] = s;
    }
    __syncthreads();

    if (t < HG) {
        float zz = b2[t];
#pragma unroll 8
        for (int k = 0; k < HG; k++) zz = fmaf(agg[k], W2[k * HG + t], zz);
        zv[t] = zz;
    }
    __syncthreads();

    {
        float gt = b_ih[t] + b_hh[t];
#pragma unroll 8
        for (int jj = 0; jj < HG; jj++) gt = fmaf(zv[jj], w_ih[t * HG + jj], gt);
        gates[t] = gt;
    }
    __syncthreads();

    if (t < HG) {
        float ig = 1.f / (1.f + expf(-gates[t]));
        float gg = tanhf(gates[2 * HG + t]);
        float og = 1.f / (1.f + expf(-gates[3 * HG + t]));
        float c = ig * gg;
        float hy = og * tanhf(c);
        hw[t] = hy * fc_w[t];
    }
    __syncthreads();
    if (t == 0) {
        float y = fc_b[0];
        for (int jj = 0; jj < HG; jj++) y += hw[jj];
        out[0] = y;
    }
}

extern "C" void kernel_launch(void* const* d_in, const int* in_sizes, int n_in,
                              void* d_out, int out_size, void* d_ws, size_t ws_size,
                              hipStream_t stream) {
    const float* x    = (const float*)d_in[0];
    const int*   ei   = (const int*)d_in[1];
    const float* W1   = (const float*)d_in[2];
    const float* b1   = (const float*)d_in[3];
    const float* W2   = (const float*)d_in[4];
    const float* b2   = (const float*)d_in[5];
    const float* w_ih = (const float*)d_in[6];
    // d_in[7] = w_hh, unused (h0 = 0)
    const float* b_ih = (const float*)d_in[8];
    const float* b_hh = (const float*)d_in[9];
    const float* fc_w = (const float*)d_in[10];
    const float* fc_b = (const float*)d_in[11];
    float* out = (float*)d_out;

    const int* src = ei;
    const int* dst = ei + N_EDGES;

    char* ws = (char*)d_ws;
    int*      deg       = (int*)(ws + OFF_DEG);
    int*      slotmap   = (int*)(ws + OFF_SLOTMAP);
    int*      cnt       = (int*)(ws + OFF_CNT);
    float*    acc       = (float*)(ws + OFF_ACC);
    unsigned* bmS1      = (unsigned*)(ws + OFF_BMS1);
    unsigned* bmNeed    = (unsigned*)(ws + OFF_BMNEED);
    int*      bcnt      = (int*)(ws + OFF_BCNT);
    int*      blist     = (int*)(ws + OFF_BLIST);
    int*      edges0    = (int*)(ws + OFF_EDGES0);
    int*      slotnodes = (int*)(ws + OFF_SLOTNODE);
    int*      mlistS    = (int*)(ws + OFF_MLISTS);
    int*      mlistD    = (int*)(ws + OFF_MLISTD);

    k_scan0<<<SCAN_BLOCKS, 256, 0, stream>>>(src, dst, (int4*)ws, bcnt, blist);
    k_build_slots<<<1, 256, 0, stream>>>(bcnt, blist, edges0, slotnodes, slotmap, cnt, bmS1);
    k_match<<<SCAN_BLOCKS, 256, 0, stream>>>(src, dst, slotmap, bmS1, bmNeed, cnt,
                                             mlistS, mlistD);
    k_deg_need<<<SCAN_BLOCKS, 256, 0, stream>>>(dst, bmS1, bmNeed, deg);
    k_contrib<<<4096, 64, 0, stream>>>(deg, cnt, mlistS, mlistD, slotnodes, x, W1, acc);
    k_final<<<1, 256, 0, stream>>>(b1, W2, b2, w_ih, b_ih, b_hh, fc_w, fc_b,
                                   deg, slotmap, cnt, edges0, acc, out);
}